// Round 12
// baseline (204.099 us; speedup 1.0000x reference)
//
#include <hip/hip_runtime.h>
#include <stdint.h>
#include <math.h>

#define EMBED 1024
#define HEADS 16
#define HDIM  64
#define SEQ   2048
#define BATCH 2

typedef __bf16 bf16x8 __attribute__((ext_vector_type(8)));
typedef float  f32x4  __attribute__((ext_vector_type(4)));
typedef unsigned short u16x8 __attribute__((ext_vector_type(8)));
typedef unsigned short u16x4 __attribute__((ext_vector_type(4)));
typedef uint32_t u32x4v __attribute__((ext_vector_type(4)));

static __device__ __forceinline__ unsigned short f2bf(float f){
  union { float f; uint32_t u; } v; v.f = f;
  uint32_t u = v.u;
  uint32_t r = (u + 0x7FFFu + ((u >> 16) & 1u)) >> 16;  // RNE
  return (unsigned short)r;
}
static __device__ __forceinline__ bf16x8 as_bf(u16x8 v){ return __builtin_bit_cast(bf16x8, v); }

static __device__ __forceinline__ uint32_t pk_bf16(float a, float b){
#if defined(__has_builtin) && __has_builtin(__builtin_amdgcn_cvt_pk_bf16_f32)
  typedef __bf16 bf16x2 __attribute__((ext_vector_type(2)));
  bf16x2 p = __builtin_amdgcn_cvt_pk_bf16_f32(a, b);
  return __builtin_bit_cast(uint32_t, p);
#else
  return (uint32_t)f2bf(a) | ((uint32_t)f2bf(b) << 16);
#endif
}

static __device__ __forceinline__ float fexp2(float x){
#if defined(__has_builtin) && __has_builtin(__builtin_amdgcn_exp2f)
  return __builtin_amdgcn_exp2f(x);
#else
  return exp2f(x);
#endif
}

// async global->LDS, 16B per lane. lp_wave must be WAVE-UNIFORM; HW adds lane*16.
static __device__ __forceinline__ void stage16(const unsigned short* gp,
                                               unsigned short* lp_wave, int lane){
#if defined(__has_builtin) && __has_builtin(__builtin_amdgcn_global_load_lds)
  __builtin_amdgcn_global_load_lds((const __attribute__((address_space(1))) void*)gp,
                                   (__attribute__((address_space(3))) void*)lp_wave,
                                   16, 0, 0);
#else
  *(u16x8*)(lp_wave + lane * 8) = *(const u16x8*)gp;
#endif
}

// ---------------- prep: cast x -> bf16, W_qkv -> wqkvT, W_out -> woutT --------------
// 1-D grid: [0,4096) cast, [4096,7168) W_qkv transpose, [7168,8192) W_out transpose.
// Safe now: woutT has its own ws slot (no v buffer anymore).
__global__ __launch_bounds__(256) void prep(
    const float* __restrict__ x,      unsigned short* __restrict__ xb,
    const float* __restrict__ W_qkv,  unsigned short* __restrict__ wqkvT,
    const float* __restrict__ W_out,  unsigned short* __restrict__ woutT)
{
  __shared__ unsigned short T[32 * 36];
  const int bid = blockIdx.x;
  const int t   = threadIdx.x;

  if (bid < 4096){
    int i = (bid * 256 + t) * 4;
    float4 v = *(const float4*)(x + i);
    u16x4 o;
    o[0] = f2bf(v.x); o[1] = f2bf(v.y); o[2] = f2bf(v.z); o[3] = f2bf(v.w);
    *(u16x4*)(xb + i) = o;
    return;
  }
  const float* W; unsigned short* Wt; int N, n0, k0;
  if (bid < 7168){
    int idx = bid - 4096;
    W = W_qkv; Wt = wqkvT; N = 3072;
    n0 = (idx % 96) * 32; k0 = (idx / 96) * 32;
  } else {
    int idx = bid - 7168;
    W = W_out; Wt = woutT; N = 1024;
    n0 = (idx & 31) * 32; k0 = (idx >> 5) * 32;
  }
  int kr = t >> 3, nc = (t & 7) * 4;
  float4 wv = *(const float4*)(W + (size_t)(k0 + kr) * N + n0 + nc);
  T[(nc + 0) * 36 + kr] = f2bf(wv.x);
  T[(nc + 1) * 36 + kr] = f2bf(wv.y);
  T[(nc + 2) * 36 + kr] = f2bf(wv.z);
  T[(nc + 3) * 36 + kr] = f2bf(wv.w);
  __syncthreads();
  int nr = t >> 3, kc = (t & 7) * 4;
  *(u16x4*)(Wt + (size_t)(n0 + nr) * 1024 + k0 + kc) = *(const u16x4*)&T[nr * 36 + kc];
}

// ---------------- QKV GEMM (BK=32): Q,K -> [bh][s][hd]; V -> permuted VT[bh][hd][s] --
// V epilogue: per-wave LDS transpose (XOR-swizzled qword cols) -> coalesced 16B stores.
// Permutation (attn PV A-frag order): kv = 16*hi + 4*g + r  ->  pos = g*8 + hi*4 + r.
__global__ __launch_bounds__(256) void gemm_qkv(
    const unsigned short* __restrict__ A,
    const unsigned short* __restrict__ Bt,
    const float* __restrict__ bias,
    unsigned short* __restrict__ q_ws,
    unsigned short* __restrict__ k_ws,
    unsigned short* __restrict__ vt_ws,
    int M, int N, int K)
{
  __shared__ unsigned short As[128 * 32];
  __shared__ unsigned short Bs[128 * 32];
  const int tid  = threadIdx.x;
  const int bm   = blockIdx.y, bn = blockIdx.x;
  const int w    = tid >> 6, lane = tid & 63;
  const int quad = lane >> 4, l16 = lane & 15;
  const int wm   = (w >> 1) * 64, wn = (w & 1) * 64;

  f32x4 acc[4][4] = {};

  for (int k0 = 0; k0 < K; k0 += 32) {
    #pragma unroll
    for (int i = 0; i < 2; i++){
      int c = w + i * 4;                 // 8 chunks of 16 rows x 1KB
      int row = c * 16 + (lane >> 2);
      int kg = (lane & 3) ^ (row & 3);   // swizzle folded into global addr
      stage16(A  + (size_t)(bm * 128 + row) * K + k0 + kg * 8, &As[c * 512], lane);
      stage16(Bt + (size_t)(bn * 128 + row) * K + k0 + kg * 8, &Bs[c * 512], lane);
    }
    __syncthreads();

    bf16x8 af[4], bfr[4];
    #pragma unroll
    for (int t = 0; t < 4; t++){
      int ra = wm + t * 16 + l16;
      int rb = wn + t * 16 + l16;
      af[t]  = as_bf(*(const u16x8*)&As[(ra << 5) + ((quad ^ (ra & 3)) << 3)]);
      bfr[t] = as_bf(*(const u16x8*)&Bs[(rb << 5) + ((quad ^ (rb & 3)) << 3)]);
    }
    #pragma unroll
    for (int mt = 0; mt < 4; mt++)
      #pragma unroll
      for (int nt = 0; nt < 4; nt++)
        acc[mt][nt] = __builtin_amdgcn_mfma_f32_16x16x32_bf16(af[mt], bfr[nt], acc[mt][nt], 0, 0, 0);
    __syncthreads();   // also fences As/Bs for epilogue reuse
  }

  const int which = (bn * 128) >> 10;   // block-uniform: 0=Q 1=K 2=V

  if (which == 2){
    // ---- V: in-wave LDS transpose -> permuted VT, coalesced b128 stores ----
    // Per-wave 4KB region: T[hd 64][32 sq] per pass (pass p = sq-half = mt>>1).
    // b64 qword column swizzle: qc' = qc ^ (hd & 7).
    unsigned short* T = (w < 2) ? &As[w * 2048] : &Bs[(w - 2) * 2048];
    const int h = (bn - 16) * 2 + (wn >> 6);
    const size_t bhbase = ((size_t)((bm >> 4) * HEADS + h)) * HDIM * SEQ;
    const int sgbase = (bm & 15) * 128 + wm;
    #pragma unroll
    for (int p = 0; p < 2; p++){
      // phase A: pack+write C-frags (8 ds_write_b64 / lane)
      #pragma unroll
      for (int mi = 0; mi < 2; mi++){
        int mt = p * 2 + mi;
        #pragma unroll
        for (int nt = 0; nt < 4; nt++){
          float bv = bias[bn * 128 + wn + nt * 16 + l16];
          uint32_t lo = pk_bf16(acc[mt][nt][0] + bv, acc[mt][nt][1] + bv);
          uint32_t hi = pk_bf16(acc[mt][nt][2] + bv, acc[mt][nt][3] + bv);
          int hd = nt * 16 + l16;
          int qc = (quad * 2 + mi) ^ (hd & 7);   // sq0/4 = quad*2 + hi, swizzled
          uint32_t* d2 = (uint32_t*)&T[hd * 32 + qc * 4];
          d2[0] = lo; d2[1] = hi;
        }
      }
      // phase B: read back (in-wave DS order), coalesced global stores
      #pragma unroll
      for (int i = 0; i < 4; i++){
        int id = i * 64 + lane;
        int hd = id >> 2, ch = id & 3;
        int q0 = (ch * 2) ^ (hd & 7), q1 = (ch * 2 + 1) ^ (hd & 7);
        const uint32_t* s0p = (const uint32_t*)&T[hd * 32 + q0 * 4];
        const uint32_t* s1p = (const uint32_t*)&T[hd * 32 + q1 * 4];
        u32x4v st; st[0] = s0p[0]; st[1] = s0p[1]; st[2] = s1p[0]; st[3] = s1p[1];
        *(u32x4v*)(vt_ws + bhbase + (size_t)hd * SEQ + sgbase + p * 32 + ch * 8) = st;
      }
    }
  } else {
    // ---- Q/K: R9-proven per-nt hoisted scalar path ----
    unsigned short* dst = (which == 0) ? q_ws : k_ws;
    const float scale = (which == 0) ? 0.18033688f : 1.0f;  // Q: 1/sqrt(Hd)*log2(e)
    const int b = bm >> 4;
    #pragma unroll
    for (int nt = 0; nt < 4; nt++){
      int gnb = bn * 128 + wn + nt * 16;
      int h   = (gnb & 1023) >> 6;
      int hd  = (gnb & 63) + l16;
      float bv = bias[gnb + l16];
      unsigned short* dp = dst + (size_t)(b * HEADS + h) * SEQ * HDIM + hd;
      #pragma unroll
      for (int mt = 0; mt < 4; mt++){
        int s0 = ((bm & 15) * 128) + wm + mt * 16 + quad * 4;
        #pragma unroll
        for (int r = 0; r < 4; r++)
          dp[(size_t)(s0 + r) * HDIM] = f2bf((acc[mt][nt][r] + bv) * scale);
      }
    }
  }
}

// ---------------- out-proj GEMM (BK=32, R9-proven): BM=128, BN=64 -------------------
__global__ __launch_bounds__(256) void gemm_out(
    const unsigned short* __restrict__ A,
    const unsigned short* __restrict__ Bt,
    const float* __restrict__ bias,
    float* __restrict__ Cout,
    int M, int N, int K)
{
  __shared__ unsigned short As[128 * 32];
  __shared__ unsigned short Bs[64 * 32];
  const int tid  = threadIdx.x;
  const int bm   = blockIdx.y, bn = blockIdx.x;
  const int w    = tid >> 6, lane = tid & 63;
  const int quad = lane >> 4, l16 = lane & 15;
  const int wm   = (w >> 1) * 64, wn = (w & 1) * 32;

  f32x4 acc[4][2] = {};

  for (int k0 = 0; k0 < K; k0 += 32) {
    #pragma unroll
    for (int i = 0; i < 2; i++){
      int c = w + i * 4;
      int row = c * 16 + (lane >> 2);
      int kg = (lane & 3) ^ (row & 3);
      stage16(A + (size_t)(bm * 128 + row) * K + k0 + kg * 8, &As[c * 512], lane);
    }
    {
      int c = w;                          // 4 chunks of 16 rows
      int row = c * 16 + (lane >> 2);
      int kg = (lane & 3) ^ (row & 3);
      stage16(Bt + (size_t)(bn * 64 + row) * K + k0 + kg * 8, &Bs[c * 512], lane);
    }
    __syncthreads();

    bf16x8 af[4], bfr[2];
    #pragma unroll
    for (int t = 0; t < 4; t++){
      int ra = wm + t * 16 + l16;
      af[t] = as_bf(*(const u16x8*)&As[(ra << 5) + ((quad ^ (ra & 3)) << 3)]);
    }
    #pragma unroll
    for (int t = 0; t < 2; t++){
      int rb = wn + t * 16 + l16;
      bfr[t] = as_bf(*(const u16x8*)&Bs[(rb << 5) + ((quad ^ (rb & 3)) << 3)]);
    }
    #pragma unroll
    for (int mt = 0; mt < 4; mt++)
      #pragma unroll
      for (int nt = 0; nt < 2; nt++)
        acc[mt][nt] = __builtin_amdgcn_mfma_f32_16x16x32_bf16(af[mt], bfr[nt], acc[mt][nt], 0, 0, 0);
    __syncthreads();
  }

  #pragma unroll
  for (int mt = 0; mt < 4; mt++)
    #pragma unroll
    for (int nt = 0; nt < 2; nt++)
      #pragma unroll
      for (int r = 0; r < 4; r++){
        int gm = bm * 128 + wm + mt * 16 + quad * 4 + r;
        int gn = bn * 64 + wn + nt * 16 + l16;
        Cout[(size_t)gm * N + gn] = acc[mt][nt][r] + bias[gn];
      }
}

// ---------------- flash attention (R11: mq=2, 8 waves, single-barrier dbuf) ---------
__global__ __launch_bounds__(512) void attn(
    const unsigned short* __restrict__ q_ws,
    const unsigned short* __restrict__ k_ws,
    const unsigned short* __restrict__ vt_ws,
    unsigned short* __restrict__ o_ws)
{
  __shared__ unsigned short Qs[256 * 64];     // 32KB
  __shared__ unsigned short Ks[2][64 * 64];   // 16KB
  __shared__ unsigned short VTs[2][64 * 64];  // 16KB  [d][kv-pos]
  const int tid  = threadIdx.x;
  const int qt   = blockIdx.x, bh = blockIdx.y;
  const int w    = tid >> 6, lane = tid & 63;
  const int quad = lane >> 4, l16 = lane & 15;
  const size_t base = (size_t)bh * SEQ * HDIM;

  #pragma unroll
  for (int i = 0; i < 4; i++){
    int c = w * 4 + i;
    int row = c * 8 + (lane >> 3);
    int kg = (lane & 7) ^ (row & 7);
    stage16(q_ws + base + (size_t)(qt * 256 + row) * HDIM + kg * 8, &Qs[c * 512], lane);
  }

  const int srow = w * 8 + (lane >> 3);
  const int skg  = (lane & 7) ^ (srow & 7);
  const int dofs = w * 512 + lane * 8;

  stage16(k_ws  + base + (size_t)srow * HDIM + skg * 8, &Ks[0][w * 512],  lane);
  stage16(vt_ws + base + (size_t)srow * SEQ + skg * 8,  &VTs[0][w * 512], lane);
  __syncthreads();

  bf16x8 bq[2][2];
  #pragma unroll
  for (int mq = 0; mq < 2; mq++){
    int row = w * 32 + mq * 16 + l16;
    #pragma unroll
    for (int ks = 0; ks < 2; ks++)
      bq[mq][ks] = as_bf(*(const u16x8*)&Qs[(row << 6) + ((((ks << 2) + quad) ^ (row & 7)) << 3)]);
  }

  const unsigned short* kp = k_ws  + base + (size_t)(64 + srow) * HDIM + skg * 8;
  const unsigned short* vp = vt_ws + base + (size_t)srow * SEQ + 64 + skg * 8;

  f32x4 acc[2][4] = {};
  float li[2] = {0.f, 0.f};

  for (int kt2 = 0; kt2 < SEQ / 128; kt2++){
    #pragma unroll
    for (int half = 0; half < 2; half++){
      const int cur = half;
      const int kt  = kt2 * 2 + half;
      u16x8 kpre, vpre;
      if (kt < SEQ / 64 - 1){
        kpre = *(const u16x8*)kp;  kp += 64 * HDIM;
        vpre = *(const u16x8*)vp;  vp += 64;
      }

      f32x4 sf[4][2] = {};
      #pragma unroll
      for (int ks = 0; ks < 2; ks++){
        #pragma unroll
        for (int nt = 0; nt < 4; nt++){
          int rk = nt * 16 + l16;
          bf16x8 ak = as_bf(*(const u16x8*)&Ks[cur][(rk << 6) + ((((ks << 2) + quad) ^ (rk & 7)) << 3)]);
          #pragma unroll
          for (int mq = 0; mq < 2; mq++)
            sf[nt][mq] = __builtin_amdgcn_mfma_f32_16x16x32_bf16(ak, bq[mq][ks], sf[nt][mq], 0, 0, 0);
        }
      }

      #pragma unroll
      for (int nt = 0; nt < 4; nt++)
        #pragma unroll
        for (int mq = 0; mq < 2; mq++)
          #pragma unroll
          for (int r = 0; r < 4; r++)
            sf[nt][mq][r] = fexp2(sf[nt][mq][r]);
      #pragma unroll
      for (int mq = 0; mq < 2; mq++)
        #pragma unroll
        for (int nt = 0; nt < 4; nt++)
          li[mq] += (sf[nt][mq][0] + sf[nt][mq][1]) + (sf[nt][mq][2] + sf[nt][mq][3]);

      #pragma unroll
      for (int c = 0; c < 2; c++){
        bf16x8 ap[2];
        #pragma unroll
        for (int mq = 0; mq < 2; mq++){
          u32x4v aw;
          aw[0] = pk_bf16(sf[c * 2][mq][0],     sf[c * 2][mq][1]);
          aw[1] = pk_bf16(sf[c * 2][mq][2],     sf[c * 2][mq][3]);
          aw[2] = pk_bf16(sf[c * 2 + 1][mq][0], sf[c * 2 + 1][mq][1]);
          aw[3] = pk_bf16(sf[c * 2 + 1][mq][2], sf[c * 2 + 1][mq][3]);
          ap[mq] = __builtin_bit_cast(bf16x8, aw);
        }
        #pragma unroll
        for (int nt = 0; nt < 4; nt++){
          int rv = nt * 16 + l16;
          bf16x8 bv = as_bf(*(const u16x8*)&VTs[cur][(rv << 6) + ((((c << 2) + quad) ^ (rv & 7)) << 3)]);
          #pragma unroll
          for (int mq = 0; mq < 2; mq++)
            acc[mq][nt] = __builtin_amdgcn_mfma_f32_16x16x32_bf16(ap[mq], bv, acc[mq][nt], 0, 0, 0);
        }
      }

      if (kt < SEQ / 64 - 1){
        *(u16x8*)&Ks[cur ^ 1][dofs]  = kpre;
        *(u16x8*)&VTs[cur ^ 1][dofs] = vpre;
      }
      __syncthreads();
    }
  }

  #pragma unroll
  for (int mq = 0; mq < 2; mq++){
    li[mq] += __shfl_xor(li[mq], 16);
    li[mq] += __shfl_xor(li[mq], 32);
  }
  float inv[2] = {1.0f / li[0], 1.0f / li[1]};
  float invr[2][4];
  #pragma unroll
  for (int mq = 0; mq < 2; mq++)
    #pragma unroll
    for (int r = 0; r < 4; r++)
      invr[mq][r] = __shfl(inv[mq], quad * 4 + r);

  int b = bh >> 4, h = bh & 15;
  #pragma unroll
  for (int mq = 0; mq < 2; mq++)
    #pragma unroll
    for (int nt = 0; nt < 4; nt++)
      #pragma unroll
      for (int r = 0; r < 4; r++){
        int s = qt * 256 + w * 32 + mq * 16 + quad * 4 + r;
        int d = h * 64 + nt * 16 + l16;
        o_ws[((size_t)(b * SEQ + s)) * EMBED + d] = f2bf(acc[mq][nt][r] * invr[mq][r]);
      }
}

// ---------------- launch ----------------
// ws map (40 MB, NO aliasing):
//   [0,8M)   xb (prep-w, gemm_qkv-r) -> o (attn-w, gemm_out-r)
//   [8,16M)  q      [16,24M) k      [24,32M) vt (gemm_qkv-w, attn-r)
//   [32,38M) wqkvT (prep-w, gemm_qkv-r)
//   [38,40M) woutT (prep-w, gemm_out-r)
extern "C" void kernel_launch(void* const* d_in, const int* in_sizes, int n_in,
                              void* d_out, int out_size, void* d_ws, size_t ws_size,
                              hipStream_t stream) {
  const float* x     = (const float*)d_in[0];
  const float* W_qkv = (const float*)d_in[1];
  const float* b_qkv = (const float*)d_in[2];
  const float* W_out = (const float*)d_in[3];
  const float* b_out = (const float*)d_in[4];
  float* out = (float*)d_out;

  char* ws = (char*)d_ws;
  unsigned short* xb    = (unsigned short*)(ws);
  unsigned short* q     = (unsigned short*)(ws + ((size_t)8  << 20));
  unsigned short* k     = (unsigned short*)(ws + ((size_t)16 << 20));
  unsigned short* vt    = (unsigned short*)(ws + ((size_t)24 << 20));
  unsigned short* wqkvT = (unsigned short*)(ws + ((size_t)32 << 20));
  unsigned short* woutT = (unsigned short*)(ws + ((size_t)38 << 20));
  unsigned short* o     = xb;

  prep<<<dim3(8192), dim3(256), 0, stream>>>(x, xb, W_qkv, wqkvT, W_out, woutT);

  gemm_qkv<<<dim3(24, 32), dim3(256), 0, stream>>>(
      xb, wqkvT, b_qkv, q, k, vt, 4096, 3072, 1024);

  attn<<<dim3(8, 32), dim3(512), 0, stream>>>(q, k, vt, o);

  gemm_out<<<dim3(16, 32), dim3(256), 0, stream>>>(
      o, woutT, b_out, out, 4096, 1024, 1024);
}

// Round 13
// 192.163 us; speedup vs baseline: 1.0621x; 1.0621x over previous
//
#include <hip/hip_runtime.h>
#include <stdint.h>
#include <math.h>

#define EMBED 1024
#define HEADS 16
#define HDIM  64
#define SEQ   2048
#define BATCH 2

typedef __bf16 bf16x8 __attribute__((ext_vector_type(8)));
typedef float  f32x4  __attribute__((ext_vector_type(4)));
typedef unsigned short u16x8 __attribute__((ext_vector_type(8)));
typedef unsigned short u16x4 __attribute__((ext_vector_type(4)));
typedef uint32_t u32x4v __attribute__((ext_vector_type(4)));

static __device__ __forceinline__ unsigned short f2bf(float f){
  union { float f; uint32_t u; } v; v.f = f;
  uint32_t u = v.u;
  uint32_t r = (u + 0x7FFFu + ((u >> 16) & 1u)) >> 16;  // RNE
  return (unsigned short)r;
}
static __device__ __forceinline__ bf16x8 as_bf(u16x8 v){ return __builtin_bit_cast(bf16x8, v); }

static __device__ __forceinline__ uint32_t pk_bf16(float a, float b){
#if defined(__has_builtin) && __has_builtin(__builtin_amdgcn_cvt_pk_bf16_f32)
  typedef __bf16 bf16x2 __attribute__((ext_vector_type(2)));
  bf16x2 p = __builtin_amdgcn_cvt_pk_bf16_f32(a, b);
  return __builtin_bit_cast(uint32_t, p);
#else
  return (uint32_t)f2bf(a) | ((uint32_t)f2bf(b) << 16);
#endif
}

static __device__ __forceinline__ float fexp2(float x){
#if defined(__has_builtin) && __has_builtin(__builtin_amdgcn_exp2f)
  return __builtin_amdgcn_exp2f(x);
#else
  return exp2f(x);
#endif
}

// async global->LDS, 16B per lane. lp_wave must be WAVE-UNIFORM; HW adds lane*16.
static __device__ __forceinline__ void stage16(const unsigned short* gp,
                                               unsigned short* lp_wave, int lane){
#if defined(__has_builtin) && __has_builtin(__builtin_amdgcn_global_load_lds)
  __builtin_amdgcn_global_load_lds((const __attribute__((address_space(1))) void*)gp,
                                   (__attribute__((address_space(3))) void*)lp_wave,
                                   16, 0, 0);
#else
  *(u16x8*)(lp_wave + lane * 8) = *(const u16x8*)gp;
#endif
}

// ---------------- prep: cast x -> bf16, W_qkv -> wqkvT, W_out -> woutT --------------
// 1-D grid: [0,4096) cast, [4096,7168) W_qkv transpose, [7168,8192) W_out transpose.
// Safe: woutT now has its own slot [38,40M) untouched until gemm_out.
__global__ __launch_bounds__(256) void prep(
    const float* __restrict__ x,      unsigned short* __restrict__ xb,
    const float* __restrict__ W_qkv,  unsigned short* __restrict__ wqkvT,
    const float* __restrict__ W_out,  unsigned short* __restrict__ woutT)
{
  __shared__ unsigned short T[32 * 36];
  const int bid = blockIdx.x;
  const int t   = threadIdx.x;

  if (bid < 4096){
    int i = (bid * 256 + t) * 4;
    float4 v = *(const float4*)(x + i);
    u16x4 o;
    o[0] = f2bf(v.x); o[1] = f2bf(v.y); o[2] = f2bf(v.z); o[3] = f2bf(v.w);
    *(u16x4*)(xb + i) = o;
    return;
  }
  const float* W; unsigned short* Wt; int N, n0, k0;
  if (bid < 7168){
    int idx = bid - 4096;
    W = W_qkv; Wt = wqkvT; N = 3072;
    n0 = (idx % 96) * 32; k0 = (idx / 96) * 32;
  } else {
    int idx = bid - 7168;
    W = W_out; Wt = woutT; N = 1024;
    n0 = (idx & 31) * 32; k0 = (idx >> 5) * 32;
  }
  int kr = t >> 3, nc = (t & 7) * 4;
  float4 wv = *(const float4*)(W + (size_t)(k0 + kr) * N + n0 + nc);
  T[(nc + 0) * 36 + kr] = f2bf(wv.x);
  T[(nc + 1) * 36 + kr] = f2bf(wv.y);
  T[(nc + 2) * 36 + kr] = f2bf(wv.z);
  T[(nc + 3) * 36 + kr] = f2bf(wv.w);
  __syncthreads();
  int nr = t >> 3, kc = (t & 7) * 4;
  *(u16x4*)(Wt + (size_t)(n0 + nr) * 1024 + k0 + kc) = *(const u16x4*)&T[nr * 36 + kc];
}

// ---------------- V[bh][S][Hd] -> VT[bh][Hd][S], PV-permuted cols -------------------
// pos(kv) = g*8 + hi*4 + r where kv = 16*hi + 4*g + r (S^T C-layout A-frag order).
__global__ __launch_bounds__(256) void vtrans(const unsigned short* __restrict__ V,
                                              unsigned short* __restrict__ VT){
  __shared__ unsigned short T[32 * 36];
  int t = threadIdx.x;
  int s0 = blockIdx.x * 32, d0 = blockIdx.y * 32;
  size_t base = (size_t)blockIdx.z * SEQ * HDIM;
  int sr = t >> 3, dc = (t & 7) * 4;
  u16x4 vv = *(const u16x4*)(V + base + (size_t)(s0 + sr) * HDIM + d0 + dc);
  T[(dc + 0) * 36 + sr] = vv[0];
  T[(dc + 1) * 36 + sr] = vv[1];
  T[(dc + 2) * 36 + sr] = vv[2];
  T[(dc + 3) * 36 + sr] = vv[3];
  __syncthreads();
  int dr = t >> 3, sc = (t & 7) * 4;
  int pos = (((sc >> 2) & 3) << 3) + (((sc >> 4) & 1) << 2); // g*8 + hi*4
  *(u16x4*)(VT + base + (size_t)(d0 + dr) * SEQ + s0 + pos) = *(const u16x4*)&T[dr * 36 + sc];
}

// ---------------- QKV GEMM (BK=32, R9-proven epilogue; bm on blockIdx.x for XCD) ----
__global__ __launch_bounds__(256) void gemm_qkv(
    const unsigned short* __restrict__ A,
    const unsigned short* __restrict__ Bt,
    const float* __restrict__ bias,
    unsigned short* __restrict__ q_ws,
    unsigned short* __restrict__ k_ws,
    unsigned short* __restrict__ v_ws,
    int M, int N, int K)
{
  __shared__ unsigned short As[128 * 32];
  __shared__ unsigned short Bs[128 * 32];
  const int tid  = threadIdx.x;
  const int bm   = blockIdx.x, bn = blockIdx.y;   // bm fast axis: same-B blocks share XCD
  const int w    = tid >> 6, lane = tid & 63;
  const int quad = lane >> 4, l16 = lane & 15;
  const int wm   = (w >> 1) * 64, wn = (w & 1) * 64;

  f32x4 acc[4][4] = {};

  for (int k0 = 0; k0 < K; k0 += 32) {
    #pragma unroll
    for (int i = 0; i < 2; i++){
      int c = w + i * 4;                 // 8 chunks of 16 rows x 1KB
      int row = c * 16 + (lane >> 2);
      int kg = (lane & 3) ^ (row & 3);   // swizzle folded into global addr
      stage16(A  + (size_t)(bm * 128 + row) * K + k0 + kg * 8, &As[c * 512], lane);
      stage16(Bt + (size_t)(bn * 128 + row) * K + k0 + kg * 8, &Bs[c * 512], lane);
    }
    __syncthreads();

    bf16x8 af[4], bfr[4];
    #pragma unroll
    for (int t = 0; t < 4; t++){
      int ra = wm + t * 16 + l16;
      int rb = wn + t * 16 + l16;
      af[t]  = as_bf(*(const u16x8*)&As[(ra << 5) + ((quad ^ (ra & 3)) << 3)]);
      bfr[t] = as_bf(*(const u16x8*)&Bs[(rb << 5) + ((quad ^ (rb & 3)) << 3)]);
    }
    #pragma unroll
    for (int mt = 0; mt < 4; mt++)
      #pragma unroll
      for (int nt = 0; nt < 4; nt++)
        acc[mt][nt] = __builtin_amdgcn_mfma_f32_16x16x32_bf16(af[mt], bfr[nt], acc[mt][nt], 0, 0, 0);
    __syncthreads();
  }

  const int which = (bn * 128) >> 10;   // block-uniform: 0=Q 1=K 2=V
  unsigned short* dst = (which == 0) ? q_ws : (which == 1) ? k_ws : v_ws;
  const float scale = (which == 0) ? 0.18033688f : 1.0f;  // Q: 1/sqrt(Hd)*log2(e)
  const int b = bm >> 4;
  #pragma unroll
  for (int nt = 0; nt < 4; nt++){
    int gnb = bn * 128 + wn + nt * 16;
    int h   = (gnb & 1023) >> 6;
    int hd  = (gnb & 63) + l16;
    float bv = bias[gnb + l16];
    unsigned short* dp = dst + (size_t)(b * HEADS + h) * SEQ * HDIM + hd;
    #pragma unroll
    for (int mt = 0; mt < 4; mt++){
      int s0 = ((bm & 15) * 128) + wm + mt * 16 + quad * 4;
      #pragma unroll
      for (int r = 0; r < 4; r++)
        dp[(size_t)(s0 + r) * HDIM] = f2bf((acc[mt][nt][r] + bv) * scale);
    }
  }
}

// ---------------- out-proj GEMM (BK=32): BM=128, BN=64; bm on blockIdx.x ------------
__global__ __launch_bounds__(256) void gemm_out(
    const unsigned short* __restrict__ A,
    const unsigned short* __restrict__ Bt,
    const float* __restrict__ bias,
    float* __restrict__ Cout,
    int M, int N, int K)
{
  __shared__ unsigned short As[128 * 32];
  __shared__ unsigned short Bs[64 * 32];
  const int tid  = threadIdx.x;
  const int bm   = blockIdx.x, bn = blockIdx.y;
  const int w    = tid >> 6, lane = tid & 63;
  const int quad = lane >> 4, l16 = lane & 15;
  const int wm   = (w >> 1) * 64, wn = (w & 1) * 32;

  f32x4 acc[4][2] = {};

  for (int k0 = 0; k0 < K; k0 += 32) {
    #pragma unroll
    for (int i = 0; i < 2; i++){
      int c = w + i * 4;
      int row = c * 16 + (lane >> 2);
      int kg = (lane & 3) ^ (row & 3);
      stage16(A + (size_t)(bm * 128 + row) * K + k0 + kg * 8, &As[c * 512], lane);
    }
    {
      int c = w;                          // 4 chunks of 16 rows
      int row = c * 16 + (lane >> 2);
      int kg = (lane & 3) ^ (row & 3);
      stage16(Bt + (size_t)(bn * 64 + row) * K + k0 + kg * 8, &Bs[c * 512], lane);
    }
    __syncthreads();

    bf16x8 af[4], bfr[2];
    #pragma unroll
    for (int t = 0; t < 4; t++){
      int ra = wm + t * 16 + l16;
      af[t] = as_bf(*(const u16x8*)&As[(ra << 5) + ((quad ^ (ra & 3)) << 3)]);
    }
    #pragma unroll
    for (int t = 0; t < 2; t++){
      int rb = wn + t * 16 + l16;
      bfr[t] = as_bf(*(const u16x8*)&Bs[(rb << 5) + ((quad ^ (rb & 3)) << 3)]);
    }
    #pragma unroll
    for (int mt = 0; mt < 4; mt++)
      #pragma unroll
      for (int nt = 0; nt < 2; nt++)
        acc[mt][nt] = __builtin_amdgcn_mfma_f32_16x16x32_bf16(af[mt], bfr[nt], acc[mt][nt], 0, 0, 0);
    __syncthreads();
  }

  #pragma unroll
  for (int mt = 0; mt < 4; mt++)
    #pragma unroll
    for (int nt = 0; nt < 2; nt++)
      #pragma unroll
      for (int r = 0; r < 4; r++){
        int gm = bm * 128 + wm + mt * 16 + quad * 4 + r;
        int gn = bn * 64 + wn + nt * 16 + l16;
        Cout[(size_t)gm * N + gn] = acc[mt][nt][r] + bias[gn];
      }
}

// ---------------- flash attention (R11-proven: mq=2, 8 waves, single-barrier dbuf) --
__global__ __launch_bounds__(512) void attn(
    const unsigned short* __restrict__ q_ws,
    const unsigned short* __restrict__ k_ws,
    const unsigned short* __restrict__ vt_ws,
    unsigned short* __restrict__ o_ws)
{
  __shared__ unsigned short Qs[256 * 64];     // 32KB
  __shared__ unsigned short Ks[2][64 * 64];   // 16KB
  __shared__ unsigned short VTs[2][64 * 64];  // 16KB  [d][kv-pos]
  const int tid  = threadIdx.x;
  const int qt   = blockIdx.x, bh = blockIdx.y;
  const int w    = tid >> 6, lane = tid & 63;
  const int quad = lane >> 4, l16 = lane & 15;
  const size_t base = (size_t)bh * SEQ * HDIM;

  #pragma unroll
  for (int i = 0; i < 4; i++){
    int c = w * 4 + i;
    int row = c * 8 + (lane >> 3);
    int kg = (lane & 7) ^ (row & 7);
    stage16(q_ws + base + (size_t)(qt * 256 + row) * HDIM + kg * 8, &Qs[c * 512], lane);
  }

  const int srow = w * 8 + (lane >> 3);
  const int skg  = (lane & 7) ^ (srow & 7);
  const int dofs = w * 512 + lane * 8;

  stage16(k_ws  + base + (size_t)srow * HDIM + skg * 8, &Ks[0][w * 512],  lane);
  stage16(vt_ws + base + (size_t)srow * SEQ + skg * 8,  &VTs[0][w * 512], lane);
  __syncthreads();

  bf16x8 bq[2][2];
  #pragma unroll
  for (int mq = 0; mq < 2; mq++){
    int row = w * 32 + mq * 16 + l16;
    #pragma unroll
    for (int ks = 0; ks < 2; ks++)
      bq[mq][ks] = as_bf(*(const u16x8*)&Qs[(row << 6) + ((((ks << 2) + quad) ^ (row & 7)) << 3)]);
  }

  const unsigned short* kp = k_ws  + base + (size_t)(64 + srow) * HDIM + skg * 8;
  const unsigned short* vp = vt_ws + base + (size_t)srow * SEQ + 64 + skg * 8;

  f32x4 acc[2][4] = {};
  float li[2] = {0.f, 0.f};

  for (int kt2 = 0; kt2 < SEQ / 128; kt2++){
    #pragma unroll
    for (int half = 0; half < 2; half++){
      const int cur = half;
      const int kt  = kt2 * 2 + half;
      u16x8 kpre, vpre;
      if (kt < SEQ / 64 - 1){
        kpre = *(const u16x8*)kp;  kp += 64 * HDIM;
        vpre = *(const u16x8*)vp;  vp += 64;
      }

      f32x4 sf[4][2] = {};
      #pragma unroll
      for (int ks = 0; ks < 2; ks++){
        #pragma unroll
        for (int nt = 0; nt < 4; nt++){
          int rk = nt * 16 + l16;
          bf16x8 ak = as_bf(*(const u16x8*)&Ks[cur][(rk << 6) + ((((ks << 2) + quad) ^ (rk & 7)) << 3)]);
          #pragma unroll
          for (int mq = 0; mq < 2; mq++)
            sf[nt][mq] = __builtin_amdgcn_mfma_f32_16x16x32_bf16(ak, bq[mq][ks], sf[nt][mq], 0, 0, 0);
        }
      }

      #pragma unroll
      for (int nt = 0; nt < 4; nt++)
        #pragma unroll
        for (int mq = 0; mq < 2; mq++)
          #pragma unroll
          for (int r = 0; r < 4; r++)
            sf[nt][mq][r] = fexp2(sf[nt][mq][r]);
      #pragma unroll
      for (int mq = 0; mq < 2; mq++)
        #pragma unroll
        for (int nt = 0; nt < 4; nt++)
          li[mq] += (sf[nt][mq][0] + sf[nt][mq][1]) + (sf[nt][mq][2] + sf[nt][mq][3]);

      #pragma unroll
      for (int c = 0; c < 2; c++){
        bf16x8 ap[2];
        #pragma unroll
        for (int mq = 0; mq < 2; mq++){
          u32x4v aw;
          aw[0] = pk_bf16(sf[c * 2][mq][0],     sf[c * 2][mq][1]);
          aw[1] = pk_bf16(sf[c * 2][mq][2],     sf[c * 2][mq][3]);
          aw[2] = pk_bf16(sf[c * 2 + 1][mq][0], sf[c * 2 + 1][mq][1]);
          aw[3] = pk_bf16(sf[c * 2 + 1][mq][2], sf[c * 2 + 1][mq][3]);
          ap[mq] = __builtin_bit_cast(bf16x8, aw);
        }
        #pragma unroll
        for (int nt = 0; nt < 4; nt++){
          int rv = nt * 16 + l16;
          bf16x8 bv = as_bf(*(const u16x8*)&VTs[cur][(rv << 6) + ((((c << 2) + quad) ^ (rv & 7)) << 3)]);
          #pragma unroll
          for (int mq = 0; mq < 2; mq++)
            acc[mq][nt] = __builtin_amdgcn_mfma_f32_16x16x32_bf16(ap[mq], bv, acc[mq][nt], 0, 0, 0);
        }
      }

      if (kt < SEQ / 64 - 1){
        *(u16x8*)&Ks[cur ^ 1][dofs]  = kpre;
        *(u16x8*)&VTs[cur ^ 1][dofs] = vpre;
      }
      __syncthreads();
    }
  }

  #pragma unroll
  for (int mq = 0; mq < 2; mq++){
    li[mq] += __shfl_xor(li[mq], 16);
    li[mq] += __shfl_xor(li[mq], 32);
  }
  float inv[2] = {1.0f / li[0], 1.0f / li[1]};
  float invr[2][4];
  #pragma unroll
  for (int mq = 0; mq < 2; mq++)
    #pragma unroll
    for (int r = 0; r < 4; r++)
      invr[mq][r] = __shfl(inv[mq], quad * 4 + r);

  int b = bh >> 4, h = bh & 15;
  #pragma unroll
  for (int mq = 0; mq < 2; mq++)
    #pragma unroll
    for (int nt = 0; nt < 4; nt++)
      #pragma unroll
      for (int r = 0; r < 4; r++){
        int s = qt * 256 + w * 32 + mq * 16 + quad * 4 + r;
        int d = h * 64 + nt * 16 + l16;
        o_ws[((size_t)(b * SEQ + s)) * EMBED + d] = f2bf(acc[mq][nt][r] * invr[mq][r]);
      }
}

// ---------------- launch ----------------
// ws alias table (40 MB):
//   [0,8M)   xb (prep-w, gemm_qkv-r; dead) -> vt (vtrans-w, attn-r)
//   [8,16M)  q      [16,24M) k
//   [24,32M) v (gemm_qkv-w, vtrans-r; dead) -> o (attn-w, gemm_out-r)
//   [32,38M) wqkvT (prep-w, gemm_qkv-r; dead)
//   [38,40M) woutT (prep-w, gemm_out-r)
extern "C" void kernel_launch(void* const* d_in, const int* in_sizes, int n_in,
                              void* d_out, int out_size, void* d_ws, size_t ws_size,
                              hipStream_t stream) {
  const float* x     = (const float*)d_in[0];
  const float* W_qkv = (const float*)d_in[1];
  const float* b_qkv = (const float*)d_in[2];
  const float* W_out = (const float*)d_in[3];
  const float* b_out = (const float*)d_in[4];
  float* out = (float*)d_out;

  char* ws = (char*)d_ws;
  unsigned short* xb    = (unsigned short*)(ws);
  unsigned short* vt    = (unsigned short*)(ws);                      // reuses xb
  unsigned short* q     = (unsigned short*)(ws + ((size_t)8  << 20));
  unsigned short* k     = (unsigned short*)(ws + ((size_t)16 << 20));
  unsigned short* v     = (unsigned short*)(ws + ((size_t)24 << 20));
  unsigned short* o     = (unsigned short*)(ws + ((size_t)24 << 20)); // reuses v
  unsigned short* wqkvT = (unsigned short*)(ws + ((size_t)32 << 20));
  unsigned short* woutT = (unsigned short*)(ws + ((size_t)38 << 20));

  prep<<<dim3(8192), dim3(256), 0, stream>>>(x, xb, W_qkv, wqkvT, W_out, woutT);

  gemm_qkv<<<dim3(32, 24), dim3(256), 0, stream>>>(
      xb, wqkvT, b_qkv, q, k, v, 4096, 3072, 1024);

  vtrans<<<dim3(64, 2, 32), dim3(256), 0, stream>>>(v, vt);

  attn<<<dim3(8, 32), dim3(512), 0, stream>>>(q, k, vt, o);

  gemm_out<<<dim3(32, 16), dim3(256), 0, stream>>>(
      o, woutT, b_out, out, 4096, 1024, 1024);
}